// Round 1
// baseline (4191.903 us; speedup 1.0000x reference)
//
#include <hip/hip_runtime.h>
#include <math.h>

#define D   512
#define TQ  32
#define TK  32

// ---------------- Linear: x = h @ W^T + b ----------------
// 64x64 output tile, K-chunks of 16, 256 threads, 4x4 microtile.
__global__ __launch_bounds__(256) void linear_kernel(
    const float* __restrict__ h, const float* __restrict__ W,
    const float* __restrict__ bias, float* __restrict__ x, int N)
{
    __shared__ float sA[16][68];  // [k][row]   (+4 pad: 2-way max on stores)
    __shared__ float sB[16][68];  // [k][col]
    const int tid = threadIdx.x;
    const int bi = blockIdx.x * 64;
    const int bd = blockIdx.y * 64;
    const int tx = tid & 15;
    const int ty = tid >> 4;
    const int lr = tid >> 2;         // 0..63
    const int lc = (tid & 3) << 2;   // 0,4,8,12
    float acc[4][4] = {};

    for (int k0 = 0; k0 < D; k0 += 16) {
        int ra = bi + lr; if (ra > N - 1) ra = N - 1;
        float4 va = *(const float4*)(h + (size_t)ra * D + k0 + lc);
        float4 vb = *(const float4*)(W + (size_t)(bd + lr) * D + k0 + lc);
        __syncthreads();             // protect previous iteration's reads
        sA[lc+0][lr] = va.x; sA[lc+1][lr] = va.y; sA[lc+2][lr] = va.z; sA[lc+3][lr] = va.w;
        sB[lc+0][lr] = vb.x; sB[lc+1][lr] = vb.y; sB[lc+2][lr] = vb.z; sB[lc+3][lr] = vb.w;
        __syncthreads();
        #pragma unroll
        for (int kk = 0; kk < 16; kk++) {
            float4 a4 = *(const float4*)&sA[kk][ty * 4];
            float4 b4 = *(const float4*)&sB[kk][tx * 4];
            float a[4] = {a4.x, a4.y, a4.z, a4.w};
            float b[4] = {b4.x, b4.y, b4.z, b4.w};
            #pragma unroll
            for (int u = 0; u < 4; u++)
                #pragma unroll
                for (int v = 0; v < 4; v++)
                    acc[u][v] = fmaf(a[u], b[v], acc[u][v]);
        }
    }
    float4 bv = *(const float4*)(bias + bd + tx * 4);
    #pragma unroll
    for (int u = 0; u < 4; u++) {
        int row = bi + ty * 4 + u;
        if (row < N) {
            float4 o;
            o.x = acc[u][0] + bv.x; o.y = acc[u][1] + bv.y;
            o.z = acc[u][2] + bv.z; o.w = acc[u][3] + bv.w;
            *(float4*)(x + (size_t)row * D + bd + tx * 4) = o;
        }
    }
}

// ---------------- Flash attention over ragged segments ----------------
// One workgroup = 32 queries of one segment. 256 threads: thread t handles
// query q=t>>3, dim-group g=t&7 owning dims {32c+4g..+3, c=0..15}.
// Scores use z_q . y_k ; output accumulates p * z_k.
__global__ __launch_bounds__(256) void attn_kernel(
    const float* __restrict__ h, const float* __restrict__ x,
    const int* __restrict__ lens, float* __restrict__ out,
    int N, int B)
{
    __shared__ float kbuf[TK * D];        // 64 KB, two-phase: Ky then Kz
    __shared__ float s_p[TQ][TK + 1];     // scores -> probs (padded)

    // lengths may arrive as int64 (low-word detector: lengths are never 0)
    const int is64 = (lens[1] == 0 && lens[3] == 0) ? 1 : 0;

    // map block -> (segment, qtile)
    int blk = blockIdx.x;
    int seg = -1, tile = 0, off = 0, len = 0;
    {
        int acc = 0, o = 0;
        for (int s_ = 0; s_ < B; s_++) {
            int L = is64 ? lens[2 * s_] : lens[s_];
            int nt = (L + TQ - 1) / TQ;
            if (blk < acc + nt) { seg = s_; tile = blk - acc; off = o; len = L; break; }
            acc += nt; o += L;
        }
    }
    if (seg < 0) return;

    const int tid = threadIdx.x;
    const int q  = tid >> 3;
    const int g  = tid & 7;
    const int qloc = tile * TQ + q;
    int qrow = off + qloc;
    const bool qvalid = qloc < len;
    if (qrow > N - 1) qrow = N - 1;

    // Q fragment: raw z row, 16 float4 at dims 32c+4g
    float4 Qf[16];
    {
        const float4* zr = (const float4*)(h + (size_t)qrow * D);
        #pragma unroll
        for (int c = 0; c < 16; c++) Qf[c] = zr[c * 8 + g];
    }

    float4 O[16];
    #pragma unroll
    for (int c = 0; c < 16; c++) O[c] = make_float4(0.f, 0.f, 0.f, 0.f);
    float m = -1e30f, l = 0.f;

    const int nkb = (len + TK - 1) / TK;
    for (int kb = 0; kb < nkb; kb++) {
        const int j0 = kb * TK;
        const int nval = min(TK, len - j0);

        // ---- stage Ky (projected x rows) ----
        __syncthreads();   // previous PV done with kbuf
        #pragma unroll
        for (int c = 0; c < 16; c++) {
            int f = tid + 256 * c;
            int r = f >> 7;
            int col = (f & 127) << 2;
            int gr = off + j0 + r; if (gr > N - 1) gr = N - 1;
            *(float4*)(kbuf + r * D + col) = *(const float4*)(x + (size_t)gr * D + col);
        }
        __syncthreads();

        // ---- scores S[q][j] = z_q . y_j ----
        #pragma unroll 4
        for (int j = 0; j < TK; j++) {
            const float4* kr = (const float4*)(kbuf + j * D);
            float a0 = 0, a1 = 0, a2 = 0, a3 = 0;
            #pragma unroll
            for (int c = 0; c < 16; c++) {
                float4 k4 = kr[c * 8 + g];
                a0 = fmaf(Qf[c].x, k4.x, a0);
                a1 = fmaf(Qf[c].y, k4.y, a1);
                a2 = fmaf(Qf[c].z, k4.z, a2);
                a3 = fmaf(Qf[c].w, k4.w, a3);
            }
            float sv = (a0 + a1) + (a2 + a3);
            sv += __shfl_xor(sv, 1, 8);
            sv += __shfl_xor(sv, 2, 8);
            sv += __shfl_xor(sv, 4, 8);
            if (g == 0) s_p[q][j] = (j < nval) ? sv : -1e30f;
        }
        // s_p[q][*] written/read within the same wave -> ordered, no barrier

        // ---- online softmax (each of the 8 lanes per q redundantly) ----
        float mb = -1e30f;
        #pragma unroll 8
        for (int j = 0; j < TK; j++) mb = fmaxf(mb, s_p[q][j]);
        float mnew = fmaxf(m, mb);
        float alpha = __expf(m - mnew);
        float psum = 0.f;
        #pragma unroll 8
        for (int j = 0; j < TK; j++) {
            float pv = __expf(s_p[q][j] - mnew);
            psum += pv;
            if (g == 0) s_p[q][j] = pv;
        }
        l = l * alpha + psum;
        m = mnew;
        #pragma unroll
        for (int c = 0; c < 16; c++) {
            O[c].x *= alpha; O[c].y *= alpha; O[c].z *= alpha; O[c].w *= alpha;
        }

        // ---- stage Kz (raw h rows) ----
        __syncthreads();   // score reads of kbuf done
        #pragma unroll
        for (int c = 0; c < 16; c++) {
            int f = tid + 256 * c;
            int r = f >> 7;
            int col = (f & 127) << 2;
            int gr = off + j0 + r; if (gr > N - 1) gr = N - 1;
            *(float4*)(kbuf + r * D + col) = *(const float4*)(h + (size_t)gr * D + col);
        }
        __syncthreads();

        // ---- O += p_j * z_j ----
        #pragma unroll 4
        for (int j = 0; j < TK; j++) {
            float pj = s_p[q][j];
            const float4* zr4 = (const float4*)(kbuf + j * D);
            #pragma unroll
            for (int c = 0; c < 16; c++) {
                float4 z4 = zr4[c * 8 + g];
                O[c].x = fmaf(pj, z4.x, O[c].x);
                O[c].y = fmaf(pj, z4.y, O[c].y);
                O[c].z = fmaf(pj, z4.z, O[c].z);
                O[c].w = fmaf(pj, z4.w, O[c].w);
            }
        }
    }

    if (qvalid) {
        float inv = 1.0f / l;
        float4* orow = (float4*)(out + (size_t)qrow * D);
        #pragma unroll
        for (int c = 0; c < 16; c++) {
            float4 v = O[c];
            v.x *= inv; v.y *= inv; v.z *= inv; v.w *= inv;
            orow[c * 8 + g] = v;
        }
    }
}

extern "C" void kernel_launch(void* const* d_in, const int* in_sizes, int n_in,
                              void* d_out, int out_size, void* d_ws, size_t ws_size,
                              hipStream_t stream) {
    const float* h    = (const float*)d_in[0];
    const float* W    = (const float*)d_in[1];
    const float* bias = (const float*)d_in[2];
    const int*   lens = (const int*)d_in[3];
    float* xws = (float*)d_ws;                 // x = h@W^T + b, N*D floats
    float* outp = (float*)d_out;

    const int N = in_sizes[0] / D;             // 24064
    const int B = in_sizes[3];                 // 16

    dim3 g1((N + 63) / 64, D / 64);
    linear_kernel<<<g1, 256, 0, stream>>>(h, W, bias, xws, N);

    const int nblk = N / TQ + B;               // upper bound on qtiles
    attn_kernel<<<nblk, 256, 0, stream>>>(h, xws, lens, outp, N, B);
}

// Round 2
// 582.302 us; speedup vs baseline: 7.1989x; 7.1989x over previous
//
#include <hip/hip_runtime.h>
#include <math.h>

#define D 512
#define AS1 __attribute__((address_space(1)))
#define AS3 __attribute__((address_space(3)))

typedef _Float16 f16x8 __attribute__((ext_vector_type(8)));
typedef float f32x4 __attribute__((ext_vector_type(4)));

// ---------------- Linear: x16 = fp16(h @ W^T + b) ----------------
__global__ __launch_bounds__(256) void linear_kernel(
    const float* __restrict__ h, const float* __restrict__ W,
    const float* __restrict__ bias, _Float16* __restrict__ x16, int N)
{
    __shared__ float sA[16][68];
    __shared__ float sB[16][68];
    const int tid = threadIdx.x;
    const int bi = blockIdx.x * 64;
    const int bd = blockIdx.y * 64;
    const int tx = tid & 15;
    const int ty = tid >> 4;
    const int lr = tid >> 2;
    const int lc = (tid & 3) << 2;
    float acc[4][4] = {};

    for (int k0 = 0; k0 < D; k0 += 16) {
        int ra = bi + lr; if (ra > N - 1) ra = N - 1;
        float4 va = *(const float4*)(h + (size_t)ra * D + k0 + lc);
        float4 vb = *(const float4*)(W + (size_t)(bd + lr) * D + k0 + lc);
        __syncthreads();
        sA[lc+0][lr] = va.x; sA[lc+1][lr] = va.y; sA[lc+2][lr] = va.z; sA[lc+3][lr] = va.w;
        sB[lc+0][lr] = vb.x; sB[lc+1][lr] = vb.y; sB[lc+2][lr] = vb.z; sB[lc+3][lr] = vb.w;
        __syncthreads();
        #pragma unroll
        for (int kk = 0; kk < 16; kk++) {
            float4 a4 = *(const float4*)&sA[kk][ty * 4];
            float4 b4 = *(const float4*)&sB[kk][tx * 4];
            float a[4] = {a4.x, a4.y, a4.z, a4.w};
            float b[4] = {b4.x, b4.y, b4.z, b4.w};
            #pragma unroll
            for (int u = 0; u < 4; u++)
                #pragma unroll
                for (int v = 0; v < 4; v++)
                    acc[u][v] = fmaf(a[u], b[v], acc[u][v]);
        }
    }
    float4 bv = *(const float4*)(bias + bd + tx * 4);
    #pragma unroll
    for (int u = 0; u < 4; u++) {
        int row = bi + ty * 4 + u;
        if (row < N) {
            union { _Float16 hh[4]; uint2 u2; } pk;
            pk.hh[0] = (_Float16)(acc[u][0] + bv.x);
            pk.hh[1] = (_Float16)(acc[u][1] + bv.y);
            pk.hh[2] = (_Float16)(acc[u][2] + bv.z);
            pk.hh[3] = (_Float16)(acc[u][3] + bv.w);
            *(uint2*)(x16 + (size_t)row * D + bd + tx * 4) = pk.u2;
        }
    }
}

// ---------------- Transpose: zT[d][n] = fp16(h[n][d]) ----------------
__global__ __launch_bounds__(256) void transpose_kernel(
    const float* __restrict__ h, _Float16* __restrict__ zT, int N)
{
    __shared__ float tile[64][65];
    const int t0 = blockIdx.x * 64;
    const int d0 = blockIdx.y * 64;
    const int tid = threadIdx.x;
    const int r0 = tid >> 4;
    const int c0 = (tid & 15) * 4;
    #pragma unroll
    for (int k = 0; k < 4; k++) {
        int r = r0 + k * 16;
        float4 v = *(const float4*)(h + (size_t)(t0 + r) * D + d0 + c0);
        tile[r][c0] = v.x; tile[r][c0+1] = v.y; tile[r][c0+2] = v.z; tile[r][c0+3] = v.w;
    }
    __syncthreads();
    #pragma unroll
    for (int k = 0; k < 4; k++) {
        int dd = r0 + k * 16;
        union { _Float16 hh[4]; uint2 u2; } pk;
        #pragma unroll
        for (int i = 0; i < 4; i++) pk.hh[i] = (_Float16)tile[c0 + i][dd];
        *(uint2*)(zT + (size_t)(d0 + dd) * N + t0 + c0) = pk.u2;
    }
}

// ---------------- Flash attention, fp16 MFMA ----------------
// WG = 4 waves, 64 queries (16/wave). K-blocks of 32 keys.
// mfma_f32_16x16x32_f16 layouts (per guide §3, m89/m91-verified):
//   A[m=lane&15][k=quad*8+j], B[k=quad*8+j][n=lane&15], C/D: row=quad*4+reg, col=lane&15
__global__ __launch_bounds__(256, 2) void attn2_kernel(
    const float* __restrict__ h, const _Float16* __restrict__ x16,
    const _Float16* __restrict__ zT, const int* __restrict__ lens,
    float* __restrict__ out, int N, int B)
{
    __shared__ __align__(16) unsigned char smem[79360];
    _Float16* ybuf = (_Float16*)smem;            // [32][520]  y-tile (keys x dims, padded)
    _Float16* zbuf = (_Float16*)(smem + 33280);  // [512][40]  z^T tile (dims x keys, padded)
    _Float16* pbuf = (_Float16*)(smem + 74240);  // 4 x [16][40] per-wave P scratch

    const int is64 = (lens[1] == 0 && lens[3] == 0) ? 1 : 0;

    // longest-first block -> (segment, qtile) mapping
    int blk = blockIdx.x;
    int seg = -1, tile = 0;
    {
        int acc = 0;
        for (int t = 0; t < B; t++) {
            int s = B - 1 - t;
            int Ls = is64 ? lens[2 * s] : lens[s];
            int nt = (Ls + 63) >> 6;
            if (seg < 0 && blk < acc + nt) { seg = s; tile = blk - acc; }
            acc += nt;
        }
    }
    if (seg < 0) return;
    int off = 0;
    for (int t = 0; t < seg; t++) off += is64 ? lens[2 * t] : lens[t];
    const int len = is64 ? lens[2 * seg] : lens[seg];

    const int tid  = threadIdx.x;
    const int wave = tid >> 6;
    const int lane = tid & 63;
    const int l15  = lane & 15;
    const int quad = lane >> 4;

    const int q0 = off + tile * 64 + wave * 16;   // wave's first query row

    // Q A-fragments in registers: 16 chunks x 8 fp16 (query m = l15)
    f16x8 Qf[16];
    {
        int qr = q0 + l15; if (qr > N - 1) qr = N - 1;
        const float* hr = h + (size_t)qr * D;
        #pragma unroll
        for (int c = 0; c < 16; c++) {
            float4 u = *(const float4*)(hr + c * 32 + quad * 8);
            float4 v = *(const float4*)(hr + c * 32 + quad * 8 + 4);
            f16x8 q;
            q[0] = (_Float16)u.x; q[1] = (_Float16)u.y; q[2] = (_Float16)u.z; q[3] = (_Float16)u.w;
            q[4] = (_Float16)v.x; q[5] = (_Float16)v.y; q[6] = (_Float16)v.z; q[7] = (_Float16)v.w;
            Qf[c] = q;
        }
    }

    f32x4 O[32];
    #pragma unroll
    for (int f = 0; f < 32; f++) O[f] = (f32x4){0.f, 0.f, 0.f, 0.f};
    float mR[4] = {-1e30f, -1e30f, -1e30f, -1e30f};
    float lR[4] = {0.f, 0.f, 0.f, 0.f};

    _Float16* Pw = pbuf + wave * 640;

    const int nkb = (len + 31) >> 5;
    for (int kb = 0; kb < nkb; kb++) {
        const int j0 = kb * 32;
        __syncthreads();   // prev iteration's reads of ybuf/zbuf complete

        // ---- stage y-tile (32 keys x 512 dims) via async DMA ----
        #pragma unroll
        for (int i = 0; i < 8; i++) {
            int r = wave * 8 + i;
            int gr = off + j0 + r; if (gr > N - 1) gr = N - 1;
            const _Float16* gsrc = x16 + (size_t)gr * D + lane * 8;
            __builtin_amdgcn_global_load_lds((const AS1 unsigned int*)gsrc,
                                             (AS3 unsigned int*)(ybuf + r * 520), 16, 0, 0);
        }
        // ---- stage z^T tile (512 dims x 32 keys) via VGPR path ----
        {
            const int c4 = lane & 3;
            #pragma unroll
            for (int i = 0; i < 8; i++) {
                int d = wave * 128 + i * 16 + (lane >> 2);
                uint4 v = *(const uint4*)(zT + (size_t)d * N + off + j0 + c4 * 8);
                *(uint4*)(zbuf + d * 40 + c4 * 8) = v;
            }
        }
        __syncthreads();

        // ---- scores: S[q][k] = z_q . y_k, two 16-key halves ----
        f32x4 s0 = (f32x4){0.f,0.f,0.f,0.f}, s1 = (f32x4){0.f,0.f,0.f,0.f};
        #pragma unroll
        for (int c = 0; c < 16; c++) {
            f16x8 b0 = *(const f16x8*)(ybuf + l15 * 520 + c * 32 + quad * 8);
            f16x8 b1 = *(const f16x8*)(ybuf + (16 + l15) * 520 + c * 32 + quad * 8);
            s0 = __builtin_amdgcn_mfma_f32_16x16x32_f16(Qf[c], b0, s0, 0, 0, 0);
            s1 = __builtin_amdgcn_mfma_f32_16x16x32_f16(Qf[c], b1, s1, 0, 0, 0);
        }

        // ---- mask invalid keys ----
        const int k0 = j0 + l15, k1 = j0 + 16 + l15;
        #pragma unroll
        for (int r = 0; r < 4; r++) {
            if (k0 >= len) s0[r] = -1e30f;
            if (k1 >= len) s1[r] = -1e30f;
        }

        // ---- online softmax (per query = quad*4+reg) ----
        float al[4], e0[4], e1[4];
        bool need = false;
        #pragma unroll
        for (int r = 0; r < 4; r++) {
            float t = fmaxf(s0[r], s1[r]);
            t = fmaxf(t, __shfl_xor(t, 1, 16));
            t = fmaxf(t, __shfl_xor(t, 2, 16));
            t = fmaxf(t, __shfl_xor(t, 4, 16));
            t = fmaxf(t, __shfl_xor(t, 8, 16));
            float mn = fmaxf(mR[r], t);
            al[r] = __expf(mR[r] - mn);
            mR[r] = mn;
            e0[r] = __expf(s0[r] - mn);
            e1[r] = __expf(s1[r] - mn);
            float ps = e0[r] + e1[r];
            ps += __shfl_xor(ps, 1, 16);
            ps += __shfl_xor(ps, 2, 16);
            ps += __shfl_xor(ps, 4, 16);
            ps += __shfl_xor(ps, 8, 16);
            lR[r] = lR[r] * al[r] + ps;
            need |= (al[r] != 1.0f);
        }
        // write P (fp16) to per-wave scratch: P[m=query][k=key]
        #pragma unroll
        for (int r = 0; r < 4; r++) {
            Pw[(quad * 4 + r) * 40 + l15]      = (_Float16)e0[r];
            Pw[(quad * 4 + r) * 40 + 16 + l15] = (_Float16)e1[r];
        }
        // rescale O only when a new max appeared anywhere in the wave
        if (__ballot(need)) {
            f32x4 av; av[0] = al[0]; av[1] = al[1]; av[2] = al[2]; av[3] = al[3];
            #pragma unroll
            for (int f = 0; f < 32; f++) O[f] *= av;
        }

        // ---- PV: O += P . z  (A = P from LDS, B = z^T tile) ----
        f16x8 pf = *(const f16x8*)(Pw + l15 * 40 + quad * 8);
        #pragma unroll
        for (int f = 0; f < 32; f++) {
            f16x8 zf = *(const f16x8*)(zbuf + (f * 16 + l15) * 40 + quad * 8);
            O[f] = __builtin_amdgcn_mfma_f32_16x16x32_f16(pf, zf, O[f], 0, 0, 0);
        }
    }

    // ---- epilogue: normalize and store ----
    float inv[4];
    #pragma unroll
    for (int r = 0; r < 4; r++) inv[r] = 1.0f / lR[r];
    #pragma unroll
    for (int r = 0; r < 4; r++) {
        int qloc = tile * 64 + wave * 16 + quad * 4 + r;
        if (qloc < len) {
            float* orow = out + (size_t)(off + qloc) * D + l15;
            #pragma unroll
            for (int f = 0; f < 32; f++) orow[f * 16] = O[f][r] * inv[r];
        }
    }
}

extern "C" void kernel_launch(void* const* d_in, const int* in_sizes, int n_in,
                              void* d_out, int out_size, void* d_ws, size_t ws_size,
                              hipStream_t stream) {
    const float* h    = (const float*)d_in[0];
    const float* W    = (const float*)d_in[1];
    const float* bias = (const float*)d_in[2];
    const int*   lens = (const int*)d_in[3];
    float* outp = (float*)d_out;

    const int N = in_sizes[0] / D;                 // 24064
    int B = in_sizes[3]; if (B > 16) B = 16;       // 16 segments

    _Float16* x16 = (_Float16*)d_ws;                                  // N*D fp16
    _Float16* zT  = (_Float16*)((char*)d_ws + (size_t)N * D * 2);     // D*N fp16

    dim3 g1((N + 63) / 64, D / 64);
    linear_kernel<<<g1, 256, 0, stream>>>(h, W, bias, x16, N);

    dim3 g2(N / 64, D / 64);
    transpose_kernel<<<g2, 256, 0, stream>>>(h, zT, N);

    const int nblk = N / 64 + B;                   // ceil-tile upper bound
    attn2_kernel<<<nblk, 256, 0, stream>>>(h, x16, zT, lens, outp, N, B);
}